// Round 14
// baseline (159.994 us; speedup 1.0000x reference)
//
#include <hip/hip_runtime.h>
#include <math.h>

#define N1 4096
#define N2 1024
#define C1 128
#define C2 256
#define CIN 384
#define H 256
#define BATCH 16
#define BN_EPS 1e-5f

typedef __attribute__((ext_vector_type(8))) short bf16x8;
typedef __attribute__((ext_vector_type(4))) float f32x4;

__device__ inline float bf2f(short s) {
    union { unsigned u; float f; } x;
    x.u = ((unsigned)(unsigned short)s) << 16;
    return x.f;
}
__device__ inline short f2bf(float f) {
    union { float f; unsigned u; } x; x.f = f;
    unsigned r = x.u + 0x7fffu + ((x.u >> 16) & 1u);
    return (short)(r >> 16);
}

typedef const __attribute__((address_space(1))) unsigned int guint;
typedef __attribute__((address_space(3))) unsigned int luint;
__device__ inline void gll16(const void* g, void* l) {
    __builtin_amdgcn_global_load_lds((guint*)g, (luint*)l, 16, 0, 0);
}

// ---------------- KNN v4: 512 thr, 8-way split, branchless exact top-3 ----------------
__global__ __launch_bounds__(512)
void knn_kernel(const float* __restrict__ c1, const float* __restrict__ c2,
                float4* __restrict__ pk) {
    __shared__ __align__(16) float4 sc[N2];
    __shared__ float md[64 * 25];
    __shared__ int   mi[64 * 25];
    const int b = blockIdx.y;
    const float* c2b = c2 + (size_t)b * 3 * N2;
    for (int j = threadIdx.x; j < N2; j += 512) {
        float xx = c2b[j], yy = c2b[N2 + j], zz = c2b[2 * N2 + j];
        sc[j] = make_float4(-2.f * xx, -2.f * yy, -2.f * zz, xx * xx + yy * yy + zz * zz);
    }
    __syncthreads();

    const int t = threadIdx.x;
    const int q = t & 63;
    const int oct = t >> 6;
    const int n = blockIdx.x * 64 + q;
    const float* c1b = c1 + (size_t)b * 3 * N1;
    const float x = c1b[n], y = c1b[N1 + n], z = c1b[2 * N1 + n];

    float d0 = 3.4e38f, d1 = 3.4e38f, d2 = 3.4e38f;
    int i0 = 0, i1 = 0, i2 = 0;
    const int j0 = oct * 128;
    #pragma unroll 8
    for (int jj = 0; jj < 128; ++jj) {
        const int j = j0 + jj;
        float4 cc = sc[j];
        float d = fmaf(x, cc.x, fmaf(y, cc.y, fmaf(z, cc.z, cc.w)));
        bool c0v = d < d0, c1v = d < d1, c2v = d < d2;
        i2 = c1v ? i1 : (c2v ? j : i2);
        i1 = c0v ? i0 : (c1v ? j : i1);
        i0 = c0v ? j  : i0;
        d2 = __builtin_amdgcn_fmed3f(d1, d2, d);
        d1 = __builtin_amdgcn_fmed3f(d0, d1, d);
        d0 = fminf(d0, d);
    }
    const int mb = q * 25 + oct * 3;
    md[mb + 0] = d0; md[mb + 1] = d1; md[mb + 2] = d2;
    mi[mb + 0] = i0; mi[mb + 1] = i1; mi[mb + 2] = i2;
    __syncthreads();

    if (t < 64) {
        float e0 = 3.4e38f, e1 = 3.4e38f, e2 = 3.4e38f;
        int a0 = 0, a1 = 0, a2 = 0;
        #pragma unroll
        for (int r = 0; r < 24; ++r) {
            const int rr = t * 25 + r;
            float d = md[rr]; int j = mi[rr];
            bool c0 = d < e0, c1v = d < e1, c2v = d < e2;
            e2 = c1v ? e1 : (c2v ? d : e2);  a2 = c1v ? a1 : (c2v ? j : a2);
            e1 = c0 ? e0 : (c1v ? d : e1);   a1 = c0 ? a0 : (c1v ? j : a1);
            e0 = c0 ? d  : e0;               a0 = c0 ? j  : a0;
        }
        const float s1 = x * x + y * y + z * z;
        float r0 = 1.0f / (e0 + s1 + 1e-8f);
        float r1 = 1.0f / (e1 + s1 + 1e-8f);
        float r2 = 1.0f / (e2 + s1 + 1e-8f);
        float rs = r0 + r1 + r2;
        unsigned pack = (unsigned)a0 | ((unsigned)a1 << 10) | ((unsigned)a2 << 20);
        pk[(size_t)b * N1 + n] = make_float4(__uint_as_float(pack), r0 / rs, r1 / rs, r2 / rs);
    }
}

// ---------------- Prep: W [256][K] f32 -> swizzled bf16 [K/8][256][8] ----------------
__global__ __launch_bounds__(256)
void prep_w(const float* __restrict__ W, short* __restrict__ Wsw, int K) {
    const int nkb = K >> 3;
    const int id = blockIdx.x * 256 + threadIdx.x;
    if (id >= 256 * nkb) return;
    const int m = id / nkb, kb = id % nkb;
    const float* src = W + (size_t)m * K + kb * 8;
    bf16x8 v;
    #pragma unroll
    for (int j = 0; j < 8; ++j) v[j] = f2bf(src[j]);
    *(bf16x8*)(Wsw + ((size_t)kb * 256 + m) * 8) = v;
}

// ---------------- Transpose f2 [b][c][j] f32 -> f2t [b][j][c] bf16 ----------------
__global__ __launch_bounds__(256)
void transpose_f2(const float* __restrict__ f2, short* __restrict__ f2t) {
    __shared__ float st[32][33];
    const int j0 = blockIdx.x * 32, c0 = blockIdx.y * 32, b = blockIdx.z;
    const int t = threadIdx.x;
    {
        const int cc = t >> 3, jj = (t & 7) * 4;
        const float* src = f2 + ((size_t)b * C2 + c0 + cc) * N2 + j0 + jj;
        float4 v = *(const float4*)src;
        st[cc][jj + 0] = v.x; st[cc][jj + 1] = v.y;
        st[cc][jj + 2] = v.z; st[cc][jj + 3] = v.w;
    }
    __syncthreads();
    {
        const int j = t >> 3, cb = (t & 7) * 4;
        short4 v = { f2bf(st[cb + 0][j]), f2bf(st[cb + 1][j]),
                     f2bf(st[cb + 2][j]), f2bf(st[cb + 3][j]) };
        *(short4*)(f2t + ((size_t)b * N2 + j0 + j) * C2 + c0 + cb) = v;
    }
}

// ---------------- GEMM1: persistent blocks, BN=32, rolling 2-buffer tile pipeline -------
// BM=256, BN=32, 256 thr / 4 waves, wave 64(M)x32(N), acc 4x2 (32 AGPR).
// 2048 tiles over 768 blocks (blocks <512: 3 tiles, else 2). stage(t+1) VALU-gathers
// issue before compute(t) -> loads land under 96 MFMAs; one barrier per tile.
__global__ __launch_bounds__(256)
void gemm1_kernel(const short* __restrict__ Wsw,
                  const float* __restrict__ f1, const short* __restrict__ f2t,
                  const float4* __restrict__ pk,
                  short* __restrict__ Ykc, float2* __restrict__ P) {
    __shared__ __align__(16) short B_lds[2][48][32][8];   // 48 KB

    const int t = threadIdx.x;
    const int blk = blockIdx.x;
    const int ntile = (blk < 512) ? 3 : 2;

    const int lane = t & 63, wv = t >> 6;
    const int wm = wv;
    const int l16 = lane & 15, lq = lane >> 4;

    auto stage = [&](int tile, int bufi) {
        const int bb = tile >> 7;
        const int n0t = (tile & 127) * 32;
        // interp rows kb 16..47: thread owns col t&31, kb-chunks i*8 + (t>>5)
        const int col = t & 31, kq = t >> 5;
        float4 pv = pk[(size_t)bb * N1 + n0t + col];
        unsigned u = __float_as_uint(pv.x);
        const short* rr0 = f2t + ((size_t)bb * N2 + (u & 1023u)) * C2;
        const short* rr1 = f2t + ((size_t)bb * N2 + ((u >> 10) & 1023u)) * C2;
        const short* rr2 = f2t + ((size_t)bb * N2 + ((u >> 20) & 1023u)) * C2;
        #pragma unroll
        for (int i = 0; i < 4; ++i) {
            const int kbl = i * 8 + kq;                 // 0..31
            bf16x8 g0 = *(const bf16x8*)(rr0 + kbl * 8);
            bf16x8 g1 = *(const bf16x8*)(rr1 + kbl * 8);
            bf16x8 g2 = *(const bf16x8*)(rr2 + kbl * 8);
            bf16x8 o;
            #pragma unroll
            for (int e = 0; e < 8; ++e)
                o[e] = f2bf(fmaf(pv.w, bf2f(g2[e]), fmaf(pv.z, bf2f(g1[e]), pv.y * bf2f(g0[e]))));
            *(bf16x8*)&B_lds[bufi][16 + kbl][col][0] = o;
        }
        // f1 rows kb 0..15: thread owns kb=t>>4, col-pair=(t&15)*2
        const float* f1b = f1 + (size_t)bb * C1 * N1;
        const int kbt = t >> 4, col2 = (t & 15) * 2;
        bf16x8 p0, p1;
        #pragma unroll
        for (int e = 0; e < 8; ++e) {
            float2 v = *(const float2*)(f1b + (size_t)(kbt * 8 + e) * N1 + n0t + col2);
            p0[e] = f2bf(v.x); p1[e] = f2bf(v.y);
        }
        *(bf16x8*)&B_lds[bufi][kbt][col2][0]     = p0;
        *(bf16x8*)&B_lds[bufi][kbt][col2 + 1][0] = p1;
    };

    stage(blk, 0);
    __syncthreads();

    int buf = 0;
    for (int ti = 0; ti < ntile; ++ti) {
        const int tile = blk + ti * 768;
        if (ti + 1 < ntile) stage(blk + (ti + 1) * 768, buf ^ 1);

        f32x4 acc[4][2];
        #pragma unroll
        for (int i = 0; i < 4; ++i) {
            acc[i][0] = (f32x4){0.f, 0.f, 0.f, 0.f};
            acc[i][1] = (f32x4){0.f, 0.f, 0.f, 0.f};
        }
        #pragma unroll
        for (int s = 0; s < 12; ++s) {
            bf16x8 a[4], bb4[2];
            const short* ap = Wsw + ((size_t)(s * 4 + lq) * 256 + wm * 64 + l16) * 8;
            #pragma unroll
            for (int f = 0; f < 4; ++f)
                a[f] = *(const bf16x8*)(ap + (size_t)f * 16 * 8);
            bb4[0] = *(const bf16x8*)&B_lds[buf][s * 4 + lq][l16][0];
            bb4[1] = *(const bf16x8*)&B_lds[buf][s * 4 + lq][16 + l16][0];
            #pragma unroll
            for (int i = 0; i < 4; ++i) {
                acc[i][0] = __builtin_amdgcn_mfma_f32_16x16x32_bf16(a[i], bb4[0], acc[i][0], 0, 0, 0);
                acc[i][1] = __builtin_amdgcn_mfma_f32_16x16x32_bf16(a[i], bb4[1], acc[i][1], 0, 0, 0);
            }
        }

        // epilogue: kc store
        const int bb = tile >> 7;
        const int n0t = (tile & 127) * 32;
        short* Yb = Ykc + (size_t)bb * 32 * N1 * 8;
        #pragma unroll
        for (int i = 0; i < 4; ++i) {
            const int kb = wm * 8 + i * 2 + (lq >> 1);
            const int kr0 = (lq & 1) * 4;
            #pragma unroll
            for (int j = 0; j < 2; ++j) {
                const int n = n0t + j * 16 + l16;
                short4 v = { f2bf(acc[i][j][0]), f2bf(acc[i][j][1]),
                             f2bf(acc[i][j][2]), f2bf(acc[i][j][3]) };
                *(short4*)(Yb + ((size_t)kb * N1 + n) * 8 + kr0) = v;
            }
        }
        // BN partials
        #pragma unroll
        for (int i = 0; i < 4; ++i) {
            #pragma unroll
            for (int r = 0; r < 4; ++r) {
                float s = acc[i][0][r] + acc[i][1][r];
                float qq = acc[i][0][r] * acc[i][0][r] + acc[i][1][r] * acc[i][1][r];
                #pragma unroll
                for (int msk = 1; msk < 16; msk <<= 1) {
                    s  += __shfl_xor(s, msk);
                    qq += __shfl_xor(qq, msk);
                }
                if (l16 == 0) {
                    const int c = wm * 64 + i * 16 + lq * 4 + r;
                    P[(size_t)c * 2048 + tile] = make_float2(s, qq);
                }
            }
        }
        __syncthreads();
        buf ^= 1;
    }
}

// ---------------- GEMM2: 2 tiles/block, both staged up-front, counted vmcnt --------------
// BM=256, BN=64, 256 thr / 4 waves, acc 4x4 (64 AGPR). LDS 64 KB -> 2 blocks/CU,
// grid 512 = exactly 2/CU, one round. 64 KB gll16 in flight per block at launch.
__global__ __launch_bounds__(256)
void gemm2_kernel(const short* __restrict__ Wsw, const short* __restrict__ y1kc,
                  const float* __restrict__ scale, const float* __restrict__ shift,
                  short* __restrict__ Ykc, float2* __restrict__ P) {
    __shared__ __align__(16) short B_lds[2][32][64][8];   // 64 KB
    __shared__ float sc_s[256], sh_s[256];

    const int t = threadIdx.x;
    const int blk = blockIdx.x;
    const int lane = t & 63, wv = t >> 6;
    const int wm = wv;
    const int l16 = lane & 15, lq = lane >> 4;

    sc_s[t] = scale[t]; sh_s[t] = shift[t];
    __syncthreads();                      // drain ALL vmem -> vmcnt counting below is exact

    auto stage = [&](int tile, int bufi) {
        const int bb = tile >> 6;
        const int n0t = (tile & 63) * 64;
        #pragma unroll
        for (int i = 0; i < 8; ++i) {
            const int u = wv * 8 + i;                   // kb row 0..31
            const short* g = y1kc + (((size_t)bb * 32 + u) * N1 + n0t + lane) * 8;
            gll16(g, &B_lds[bufi][u][0][0]);
        }
    };

    stage(blk, 0);                        // 8 gll16
    stage(blk + 512, 1);                  // +8 -> 16 outstanding

    asm volatile("s_waitcnt vmcnt(8)" ::: "memory");   // tile-0 staged; tile-1 flying
    __builtin_amdgcn_sched_barrier(0);
    __builtin_amdgcn_s_barrier();
    __builtin_amdgcn_sched_barrier(0);

    #pragma unroll
    for (int ti = 0; ti < 2; ++ti) {
        const int tile = blk + ti * 512;
        const int bb = tile >> 6;
        const int n0t = (tile & 63) * 64;

        f32x4 acc[4][4];
        #pragma unroll
        for (int i = 0; i < 4; ++i)
            #pragma unroll
            for (int j = 0; j < 4; ++j)
                acc[i][j] = (f32x4){0.f, 0.f, 0.f, 0.f};

        #pragma unroll
        for (int s = 0; s < 8; ++s) {
            bf16x8 a[4], bb4[4];
            const short* ap = Wsw + ((size_t)(s * 4 + lq) * 256 + wm * 64 + l16) * 8;
            #pragma unroll
            for (int f = 0; f < 4; ++f)
                a[f] = *(const bf16x8*)(ap + (size_t)f * 16 * 8);
            const int k0 = s * 32 + lq * 8;
            float sck[8], shk[8];
            #pragma unroll
            for (int e = 0; e < 8; ++e) { sck[e] = sc_s[k0 + e]; shk[e] = sh_s[k0 + e]; }
            #pragma unroll
            for (int f = 0; f < 4; ++f) {
                bf16x8 raw = *(const bf16x8*)&B_lds[ti][s * 4 + lq][f * 16 + l16][0];
                #pragma unroll
                for (int e = 0; e < 8; ++e)
                    bb4[f][e] = f2bf(fmaxf(fmaf(bf2f(raw[e]), sck[e], shk[e]), 0.f));
            }
            #pragma unroll
            for (int i = 0; i < 4; ++i)
                #pragma unroll
                for (int j = 0; j < 4; ++j)
                    acc[i][j] = __builtin_amdgcn_mfma_f32_16x16x32_bf16(a[i], bb4[j], acc[i][j], 0, 0, 0);
        }

        short* Yb = Ykc + (size_t)bb * 32 * N1 * 8;
        #pragma unroll
        for (int i = 0; i < 4; ++i) {
            const int kb = wm * 8 + i * 2 + (lq >> 1);
            const int kr0 = (lq & 1) * 4;
            #pragma unroll
            for (int j = 0; j < 4; ++j) {
                const int n = n0t + j * 16 + l16;
                short4 v = { f2bf(acc[i][j][0]), f2bf(acc[i][j][1]),
                             f2bf(acc[i][j][2]), f2bf(acc[i][j][3]) };
                *(short4*)(Yb + ((size_t)kb * N1 + n) * 8 + kr0) = v;
            }
        }
        #pragma unroll
        for (int i = 0; i < 4; ++i) {
            #pragma unroll
            for (int r = 0; r < 4; ++r) {
                float s = 0.f, qq = 0.f;
                #pragma unroll
                for (int j = 0; j < 4; ++j) {
                    float xv = acc[i][j][r];
                    s += xv; qq += xv * xv;
                }
                #pragma unroll
                for (int msk = 1; msk < 16; msk <<= 1) {
                    s  += __shfl_xor(s, msk);
                    qq += __shfl_xor(qq, msk);
                }
                if (l16 == 0) {
                    const int c = wm * 64 + i * 16 + lq * 4 + r;
                    P[(size_t)c * 1024 + tile] = make_float2(s, qq);
                }
            }
        }
        if (ti == 0) __syncthreads();     // tile-1's gll16 long landed; full drain
    }
}

// ---------------- BN reduce: partials [256][NP] -> scale/shift ----------------
template<int NP>
__global__ __launch_bounds__(256)
void bn_reduce(const float2* __restrict__ P, const float* __restrict__ g,
               const float* __restrict__ be, float* __restrict__ scale,
               float* __restrict__ shift) {
    const int c = blockIdx.x, t = threadIdx.x;
    float s = 0.f, q = 0.f;
    #pragma unroll
    for (int r = 0; r < NP / 256; ++r) {
        float2 v = P[(size_t)c * NP + r * 256 + t];
        s += v.x; q += v.y;
    }
    __shared__ float ss[256], sq[256];
    ss[t] = s; sq[t] = q;
    __syncthreads();
    for (int o = 128; o > 0; o >>= 1) {
        if (t < o) { ss[t] += ss[t + o]; sq[t] += sq[t + o]; }
        __syncthreads();
    }
    if (t == 0) {
        const float inv = 1.0f / (float)(BATCH * N1);
        float mean = ss[0] * inv;
        float var  = sq[0] * inv - mean * mean;
        float sc = g[c] / sqrtf(var + BN_EPS);
        scale[c] = sc;
        shift[c] = be[c] - mean * sc;
    }
}

// ---------------- Final BN2+ReLU: y2kc -> f32 out (normal layout) ----------------
__global__ __launch_bounds__(256)
void final_bn_relu(const short* __restrict__ y2kc, const float* __restrict__ scale,
                   const float* __restrict__ shift, float* __restrict__ out) {
    const int t = threadIdx.x;
    const int n0 = blockIdx.x * 1024 + t * 4;
    const int kb = blockIdx.y, b = blockIdx.z;
    const short* src = y2kc + ((size_t)(b * 32 + kb) * N1 + n0) * 8;
    bf16x8 v0 = *(const bf16x8*)(src);
    bf16x8 v1 = *(const bf16x8*)(src + 8);
    bf16x8 v2 = *(const bf16x8*)(src + 16);
    bf16x8 v3 = *(const bf16x8*)(src + 24);
    #pragma unroll
    for (int e = 0; e < 8; ++e) {
        const float sc = scale[kb * 8 + e], sh = shift[kb * 8 + e];
        float4 o;
        o.x = fmaxf(fmaf(bf2f(v0[e]), sc, sh), 0.f);
        o.y = fmaxf(fmaf(bf2f(v1[e]), sc, sh), 0.f);
        o.z = fmaxf(fmaf(bf2f(v2[e]), sc, sh), 0.f);
        o.w = fmaxf(fmaf(bf2f(v3[e]), sc, sh), 0.f);
        *(float4*)(out + ((size_t)(b * 256 + kb * 8 + e) * N1) + n0) = o;
    }
}

extern "C" void kernel_launch(void* const* d_in, const int* in_sizes, int n_in,
                              void* d_out, int out_size, void* d_ws, size_t ws_size,
                              hipStream_t stream) {
    const float* c1  = (const float*)d_in[0];
    const float* c2  = (const float*)d_in[1];
    const float* f1  = (const float*)d_in[2];
    const float* f2  = (const float*)d_in[3];
    const float* W1  = (const float*)d_in[4];
    const float* g1  = (const float*)d_in[6];
    const float* be1 = (const float*)d_in[7];
    const float* W2  = (const float*)d_in[8];
    const float* g2  = (const float*)d_in[10];
    const float* be2 = (const float*)d_in[11];
    float* out = (float*)d_out;

    // ws regions (sequential overlap, peak ~66.4 MiB):
    // [0,32):   y1kc (gemm1 -> gemm2)
    // [32,40):  f2t (transpose -> gemm1)      } both dead before y2kc
    // [40,41):  pk  (knn -> gemm1)            } (gemm2 -> final) takes [32,64)
    // [41,45):  P1  (gemm1 -> bn_reduce1)     }
    // [64..):   W1s | W2s | P2 (2 MiB) | scales
    char* ws = (char*)d_ws;
    short*  y1kc = (short*)ws;
    short*  f2t  = (short*)(ws + (32u << 20));
    float4* pk   = (float4*)(ws + (40u << 20));
    float2* P1   = (float2*)(ws + (41u << 20));
    short*  y2kc = (short*)(ws + (32u << 20));
    short*  W1s  = (short*)(ws + (64u << 20));
    short*  W2s  = (short*)(ws + (64u << 20) + (192u << 10));
    float2* P2   = (float2*)(ws + (64u << 20) + (320u << 10));
    float* scale1 = (float*)(ws + (64u << 20) + (320u << 10) + (2u << 20));
    float* shift1 = scale1 + 256;
    float* scale2 = shift1 + 256;
    float* shift2 = scale2 + 256;

    prep_w<<<48, 256, 0, stream>>>(W1, W1s, CIN);
    prep_w<<<32, 256, 0, stream>>>(W2, W2s, H);
    transpose_f2<<<dim3(N2 / 32, C2 / 32, BATCH), 256, 0, stream>>>(f2, f2t);
    knn_kernel<<<dim3(N1 / 64, BATCH), 512, 0, stream>>>(c1, c2, pk);

    gemm1_kernel<<<768, 256, 0, stream>>>(W1s, f1, f2t, pk, y1kc, P1);
    bn_reduce<2048><<<256, 256, 0, stream>>>(P1, g1, be1, scale1, shift1);

    gemm2_kernel<<<512, 256, 0, stream>>>(W2s, y1kc, scale1, shift1, y2kc, P2);
    bn_reduce<1024><<<256, 256, 0, stream>>>(P2, g2, be2, scale2, shift2);

    final_bn_relu<<<dim3(N1 / 1024, 32, BATCH), 256, 0, stream>>>(y2kc, scale2, shift2, out);
}

// Round 15
// 128.323 us; speedup vs baseline: 1.2468x; 1.2468x over previous
//
#include <hip/hip_runtime.h>
#include <math.h>

#define N1 4096
#define N2 1024
#define C1 128
#define C2 256
#define CIN 384
#define H 256
#define BATCH 16
#define BN_EPS 1e-5f

typedef __attribute__((ext_vector_type(8))) short bf16x8;
typedef __attribute__((ext_vector_type(4))) float f32x4;

__device__ inline float bf2f(short s) {
    union { unsigned u; float f; } x;
    x.u = ((unsigned)(unsigned short)s) << 16;
    return x.f;
}
__device__ inline short f2bf(float f) {
    union { float f; unsigned u; } x; x.f = f;
    unsigned r = x.u + 0x7fffu + ((x.u >> 16) & 1u);
    return (short)(r >> 16);
}

typedef const __attribute__((address_space(1))) unsigned int guint;
typedef __attribute__((address_space(3))) unsigned int luint;
__device__ inline void gll16(const void* g, void* l) {
    __builtin_amdgcn_global_load_lds((guint*)g, (luint*)l, 16, 0, 0);
}

// ---------------- Fused prep: knn | transpose_f2 | prep_w, block-range dispatch ----------
// blocks [0,1024):        knn (b=blk>>6, n-group=blk&63), 512 thr, 8-way split
// blocks [1024,3072):     transpose_f2, 2 tiles per block (half = t>>8)
// blocks [3072,3096):     prep_w W1 (K=384)
// blocks [3096,3112):     prep_w W2 (K=256)
__global__ __launch_bounds__(512)
void prep_fused(const float* __restrict__ c1, const float* __restrict__ c2,
                const float* __restrict__ f2, const float* __restrict__ W1,
                const float* __restrict__ W2,
                float4* __restrict__ pk, short* __restrict__ f2t,
                short* __restrict__ W1s, short* __restrict__ W2s) {
    __shared__ __align__(16) char lds_raw[29184];
    const int blk = blockIdx.x;
    const int t = threadIdx.x;

    if (blk < 1024) {
        // ================= KNN v4 (identical math to round-13 kernel) =================
        float4* sc = (float4*)lds_raw;                       // 16384 B
        float*  md = (float*)(lds_raw + 16384);              // 6400 B
        int*    mi = (int*)(lds_raw + 16384 + 6400);         // 6400 B
        const int b = blk >> 6, ng = blk & 63;
        const float* c2b = c2 + (size_t)b * 3 * N2;
        for (int j = t; j < N2; j += 512) {
            float xx = c2b[j], yy = c2b[N2 + j], zz = c2b[2 * N2 + j];
            sc[j] = make_float4(-2.f * xx, -2.f * yy, -2.f * zz, xx * xx + yy * yy + zz * zz);
        }
        __syncthreads();

        const int q = t & 63;
        const int oct = t >> 6;
        const int n = ng * 64 + q;
        const float* c1b = c1 + (size_t)b * 3 * N1;
        const float x = c1b[n], y = c1b[N1 + n], z = c1b[2 * N1 + n];

        float d0 = 3.4e38f, d1 = 3.4e38f, d2 = 3.4e38f;
        int i0 = 0, i1 = 0, i2 = 0;
        const int j0 = oct * 128;
        #pragma unroll 8
        for (int jj = 0; jj < 128; ++jj) {
            const int j = j0 + jj;
            float4 cc = sc[j];
            float d = fmaf(x, cc.x, fmaf(y, cc.y, fmaf(z, cc.z, cc.w)));
            bool c0v = d < d0, c1v = d < d1, c2v = d < d2;
            i2 = c1v ? i1 : (c2v ? j : i2);
            i1 = c0v ? i0 : (c1v ? j : i1);
            i0 = c0v ? j  : i0;
            d2 = __builtin_amdgcn_fmed3f(d1, d2, d);
            d1 = __builtin_amdgcn_fmed3f(d0, d1, d);
            d0 = fminf(d0, d);
        }
        const int mb = q * 25 + oct * 3;
        md[mb + 0] = d0; md[mb + 1] = d1; md[mb + 2] = d2;
        mi[mb + 0] = i0; mi[mb + 1] = i1; mi[mb + 2] = i2;
        __syncthreads();

        if (t < 64) {
            float e0 = 3.4e38f, e1 = 3.4e38f, e2 = 3.4e38f;
            int a0 = 0, a1 = 0, a2 = 0;
            #pragma unroll
            for (int r = 0; r < 24; ++r) {
                const int rr = t * 25 + r;
                float d = md[rr]; int j = mi[rr];
                bool c0 = d < e0, c1v = d < e1, c2v = d < e2;
                e2 = c1v ? e1 : (c2v ? d : e2);  a2 = c1v ? a1 : (c2v ? j : a2);
                e1 = c0 ? e0 : (c1v ? d : e1);   a1 = c0 ? a0 : (c1v ? j : a1);
                e0 = c0 ? d  : e0;               a0 = c0 ? j  : a0;
            }
            const float s1 = x * x + y * y + z * z;
            float r0 = 1.0f / (e0 + s1 + 1e-8f);
            float r1 = 1.0f / (e1 + s1 + 1e-8f);
            float r2 = 1.0f / (e2 + s1 + 1e-8f);
            float rs = r0 + r1 + r2;
            unsigned pack = (unsigned)a0 | ((unsigned)a1 << 10) | ((unsigned)a2 << 20);
            pk[(size_t)b * N1 + n] = make_float4(__uint_as_float(pack), r0 / rs, r1 / rs, r2 / rs);
        }
    } else if (blk < 3072) {
        // ================= transpose_f2: two 32x32 tiles per block =================
        typedef float (*st_t)[32][33];
        st_t st = (st_t)lds_raw;                             // 2 * 8448 B
        const int half = t >> 8, tt = t & 255;
        const int tid = (blk - 1024) * 2 + half;             // 0..4095
        const int j0 = (tid & 31) * 32, c0 = ((tid >> 5) & 7) * 32, b = tid >> 8;
        {
            const int cc = tt >> 3, jj = (tt & 7) * 4;
            const float* src = f2 + ((size_t)b * C2 + c0 + cc) * N2 + j0 + jj;
            float4 v = *(const float4*)src;
            st[half][cc][jj + 0] = v.x; st[half][cc][jj + 1] = v.y;
            st[half][cc][jj + 2] = v.z; st[half][cc][jj + 3] = v.w;
        }
        __syncthreads();
        {
            const int j = tt >> 3, cb = (tt & 7) * 4;
            short4 v = { f2bf(st[half][cb + 0][j]), f2bf(st[half][cb + 1][j]),
                         f2bf(st[half][cb + 2][j]), f2bf(st[half][cb + 3][j]) };
            *(short4*)(f2t + ((size_t)b * N2 + j0 + j) * C2 + c0 + cb) = v;
        }
    } else {
        // ================= prep_w =================
        const bool w1 = (blk < 3096);
        const int K = w1 ? CIN : H;
        const int nkb = K >> 3;
        const int id = (blk - (w1 ? 3072 : 3096)) * 512 + t;
        if (id < 256 * nkb) {
            const float* W = w1 ? W1 : W2;
            short* Wsw = w1 ? W1s : W2s;
            const int m = id / nkb, kb = id % nkb;
            const float* src = W + (size_t)m * K + kb * 8;
            bf16x8 v;
            #pragma unroll
            for (int j = 0; j < 8; ++j) v[j] = f2bf(src[j]);
            *(bf16x8*)(Wsw + ((size_t)kb * 256 + m) * 8) = v;
        }
    }
}

// ---------------- B-resident MFMA GEMM (round-13 proven): one-shot LDS B-tile -----------
// BM=256 (full M), BN=64, 256 threads / 4 waves, wave = 64(M)x64(N). B read once.
// NT=12 (gemm1): B kb 0..15 from f1 (f32 reg-stage); kb 16..47 INTERP gathered from
//                f2t (L2/L3-resident) using per-column pk.
// NT=8, BN=true (gemm2): all 32 kb gll16 from y1kc; BN1+ReLU applied on fragment read.
template<int NT, bool BN>
__global__ __launch_bounds__(256)
void gemm_kernel(const short* __restrict__ Wsw,
                 const float* __restrict__ f1, const short* __restrict__ Bkc,
                 const short* __restrict__ f2t, const float4* __restrict__ pk,
                 const float* __restrict__ scale, const float* __restrict__ shift,
                 short* __restrict__ Ykc, float2* __restrict__ P) {
    constexpr bool M0 = (NT == 12);

    __shared__ __align__(16) short B_lds[4 * NT][64][8];  // 48 KB / 32 KB
    __shared__ float sc_s[256], sh_s[256];

    const int t = threadIdx.x;
    const int blk = blockIdx.x;
    const int b = blk >> 6, nt = blk & 63;
    const int n0 = nt * 64;

    const int lane = t & 63, wv = t >> 6;
    const int wm = wv;
    const int l16 = lane & 15, lq = lane >> 4;

    if (BN) { sc_s[t] = scale[t]; sh_s[t] = shift[t]; }

    if (M0) {
        const int col = t & 63;
        const int kq  = t >> 6;
        float4 pv = pk[(size_t)b * N1 + n0 + col];
        unsigned u = __float_as_uint(pv.x);
        const short* rr0 = f2t + ((size_t)b * N2 + (u & 1023u)) * C2;
        const short* rr1 = f2t + ((size_t)b * N2 + ((u >> 10) & 1023u)) * C2;
        const short* rr2 = f2t + ((size_t)b * N2 + ((u >> 20) & 1023u)) * C2;
        #pragma unroll
        for (int i = 0; i < 8; ++i) {
            const int kbl = i * 4 + kq;
            bf16x8 g0 = *(const bf16x8*)(rr0 + kbl * 8);
            bf16x8 g1 = *(const bf16x8*)(rr1 + kbl * 8);
            bf16x8 g2 = *(const bf16x8*)(rr2 + kbl * 8);
            bf16x8 o;
            #pragma unroll
            for (int e = 0; e < 8; ++e)
                o[e] = f2bf(fmaf(pv.w, bf2f(g2[e]), fmaf(pv.z, bf2f(g1[e]), pv.y * bf2f(g0[e]))));
            *(bf16x8*)&B_lds[16 + kbl][col][0] = o;
        }
        const float* f1b = f1 + (size_t)b * C1 * N1;
        const int kbt = t >> 4, nq = (t & 15) * 4;
        float4 fv[8];
        #pragma unroll
        for (int e = 0; e < 8; ++e)
            fv[e] = *(const float4*)(f1b + (size_t)(kbt * 8 + e) * N1 + n0 + nq);
        #pragma unroll
        for (int j = 0; j < 4; ++j) {
            bf16x8 pw;
            pw[0] = f2bf(j == 0 ? fv[0].x : j == 1 ? fv[0].y : j == 2 ? fv[0].z : fv[0].w);
            pw[1] = f2bf(j == 0 ? fv[1].x : j == 1 ? fv[1].y : j == 2 ? fv[1].z : fv[1].w);
            pw[2] = f2bf(j == 0 ? fv[2].x : j == 1 ? fv[2].y : j == 2 ? fv[2].z : fv[2].w);
            pw[3] = f2bf(j == 0 ? fv[3].x : j == 1 ? fv[3].y : j == 2 ? fv[3].z : fv[3].w);
            pw[4] = f2bf(j == 0 ? fv[4].x : j == 1 ? fv[4].y : j == 2 ? fv[4].z : fv[4].w);
            pw[5] = f2bf(j == 0 ? fv[5].x : j == 1 ? fv[5].y : j == 2 ? fv[5].z : fv[5].w);
            pw[6] = f2bf(j == 0 ? fv[6].x : j == 1 ? fv[6].y : j == 2 ? fv[6].z : fv[6].w);
            pw[7] = f2bf(j == 0 ? fv[7].x : j == 1 ? fv[7].y : j == 2 ? fv[7].z : fv[7].w);
            *(bf16x8*)&B_lds[kbt][nq + j][0] = pw;
        }
    } else {
        const short* Bb = Bkc + (size_t)b * 32 * N1 * 8;
        #pragma unroll
        for (int i = 0; i < 8; ++i) {
            const int u = wv * 8 + i;
            const short* g = Bb + ((size_t)u * N1 + n0 + lane) * 8;
            gll16(g, &B_lds[u][0][0]);
        }
    }
    __syncthreads();

    f32x4 acc[4][4];
    #pragma unroll
    for (int i = 0; i < 4; ++i)
        #pragma unroll
        for (int j = 0; j < 4; ++j)
            acc[i][j] = (f32x4){0.f, 0.f, 0.f, 0.f};

    #pragma unroll
    for (int s = 0; s < NT; ++s) {
        bf16x8 a[4], bb4[4];
        const short* ap = Wsw + ((size_t)(s * 4 + lq) * 256 + wm * 64 + l16) * 8;
        #pragma unroll
        for (int f = 0; f < 4; ++f)
            a[f] = *(const bf16x8*)(ap + (size_t)f * 16 * 8);
        if (BN) {
            const int k0 = s * 32 + lq * 8;
            float sck[8], shk[8];
            #pragma unroll
            for (int e = 0; e < 8; ++e) { sck[e] = sc_s[k0 + e]; shk[e] = sh_s[k0 + e]; }
            #pragma unroll
            for (int f = 0; f < 4; ++f) {
                bf16x8 raw = *(const bf16x8*)&B_lds[s * 4 + lq][f * 16 + l16][0];
                #pragma unroll
                for (int e = 0; e < 8; ++e)
                    bb4[f][e] = f2bf(fmaxf(fmaf(bf2f(raw[e]), sck[e], shk[e]), 0.f));
            }
        } else {
            #pragma unroll
            for (int f = 0; f < 4; ++f)
                bb4[f] = *(const bf16x8*)&B_lds[s * 4 + lq][f * 16 + l16][0];
        }
        #pragma unroll
        for (int i = 0; i < 4; ++i)
            #pragma unroll
            for (int j = 0; j < 4; ++j)
                acc[i][j] = __builtin_amdgcn_mfma_f32_16x16x32_bf16(a[i], bb4[j], acc[i][j], 0, 0, 0);
    }

    short* Yb = Ykc + (size_t)b * 32 * N1 * 8;
    #pragma unroll
    for (int i = 0; i < 4; ++i) {
        const int kb = wm * 8 + i * 2 + (lq >> 1);
        const int kr0 = (lq & 1) * 4;
        #pragma unroll
        for (int j = 0; j < 4; ++j) {
            const int n = n0 + j * 16 + l16;
            short4 v = { f2bf(acc[i][j][0]), f2bf(acc[i][j][1]),
                         f2bf(acc[i][j][2]), f2bf(acc[i][j][3]) };
            *(short4*)(Yb + ((size_t)kb * N1 + n) * 8 + kr0) = v;
        }
    }

    #pragma unroll
    for (int i = 0; i < 4; ++i) {
        #pragma unroll
        for (int r = 0; r < 4; ++r) {
            float s = 0.f, qq = 0.f;
            #pragma unroll
            for (int j = 0; j < 4; ++j) {
                float xv = acc[i][j][r];
                s += xv; qq += xv * xv;
            }
            #pragma unroll
            for (int msk = 1; msk < 16; msk <<= 1) {
                s  += __shfl_xor(s, msk);
                qq += __shfl_xor(qq, msk);
            }
            if (l16 == 0) {
                const int c = wm * 64 + i * 16 + lq * 4 + r;
                P[(size_t)c * 1024 + blk] = make_float2(s, qq);
            }
        }
    }
}

// ---------------- BN reduce: partials [256][1024] -> scale/shift ----------------
__global__ __launch_bounds__(256)
void bn_reduce(const float2* __restrict__ P, const float* __restrict__ g,
               const float* __restrict__ be, float* __restrict__ scale,
               float* __restrict__ shift) {
    const int c = blockIdx.x, t = threadIdx.x;
    float s = 0.f, q = 0.f;
    #pragma unroll
    for (int r = 0; r < 4; ++r) {
        float2 v = P[(size_t)c * 1024 + r * 256 + t];
        s += v.x; q += v.y;
    }
    __shared__ float ss[256], sq[256];
    ss[t] = s; sq[t] = q;
    __syncthreads();
    for (int o = 128; o > 0; o >>= 1) {
        if (t < o) { ss[t] += ss[t + o]; sq[t] += sq[t + o]; }
        __syncthreads();
    }
    if (t == 0) {
        const float inv = 1.0f / (float)(BATCH * N1);
        float mean = ss[0] * inv;
        float var  = sq[0] * inv - mean * mean;
        float sc = g[c] / sqrtf(var + BN_EPS);
        scale[c] = sc;
        shift[c] = be[c] - mean * sc;
    }
}

// ---------------- Final BN2+ReLU: y2kc -> f32 out (normal layout) ----------------
__global__ __launch_bounds__(256)
void final_bn_relu(const short* __restrict__ y2kc, const float* __restrict__ scale,
                   const float* __restrict__ shift, float* __restrict__ out) {
    const int t = threadIdx.x;
    const int n0 = blockIdx.x * 1024 + t * 4;
    const int kb = blockIdx.y, b = blockIdx.z;
    const short* src = y2kc + ((size_t)(b * 32 + kb) * N1 + n0) * 8;
    bf16x8 v0 = *(const bf16x8*)(src);
    bf16x8 v1 = *(const bf16x8*)(src + 8);
    bf16x8 v2 = *(const bf16x8*)(src + 16);
    bf16x8 v3 = *(const bf16x8*)(src + 24);
    #pragma unroll
    for (int e = 0; e < 8; ++e) {
        const float sc = scale[kb * 8 + e], sh = shift[kb * 8 + e];
        float4 o;
        o.x = fmaxf(fmaf(bf2f(v0[e]), sc, sh), 0.f);
        o.y = fmaxf(fmaf(bf2f(v1[e]), sc, sh), 0.f);
        o.z = fmaxf(fmaf(bf2f(v2[e]), sc, sh), 0.f);
        o.w = fmaxf(fmaf(bf2f(v3[e]), sc, sh), 0.f);
        *(float4*)(out + ((size_t)(b * 256 + kb * 8 + e) * N1) + n0) = o;
    }
}

extern "C" void kernel_launch(void* const* d_in, const int* in_sizes, int n_in,
                              void* d_out, int out_size, void* d_ws, size_t ws_size,
                              hipStream_t stream) {
    const float* c1  = (const float*)d_in[0];
    const float* c2  = (const float*)d_in[1];
    const float* f1  = (const float*)d_in[2];
    const float* f2  = (const float*)d_in[3];
    const float* W1  = (const float*)d_in[4];
    const float* g1  = (const float*)d_in[6];
    const float* be1 = (const float*)d_in[7];
    const float* W2  = (const float*)d_in[8];
    const float* g2  = (const float*)d_in[10];
    const float* be2 = (const float*)d_in[11];
    float* out = (float*)d_out;

    // ws regions (sequential-kernel overlap, peak ~67.6 MiB):
    // [0,32 MiB):  y1kc (gemm1 -> gemm2)
    // [32,64):     f2t (8 MiB, prep -> gemm1), then y2kc (gemm2 -> final)
    // [64..):      W1s | W2s | pk | P(2 MiB) | scales
    char* ws = (char*)d_ws;
    short*  y1kc = (short*)ws;
    short*  f2t  = (short*)(ws + (32u << 20));
    short*  y2kc = (short*)(ws + (32u << 20));
    short*  W1s  = (short*)(ws + (64u << 20));
    short*  W2s  = (short*)(ws + (64u << 20) + (256u << 10));
    float4* pk   = (float4*)(ws + (64u << 20) + (512u << 10));
    float2* P    = (float2*)(ws + (64u << 20) + (1536u << 10));
    float* scale1 = (float*)(ws + (64u << 20) + (3584u << 10));
    float* shift1 = scale1 + 256;
    float* scale2 = shift1 + 256;
    float* shift2 = scale2 + 256;

    // fused prep: knn + transpose_f2 + prep_w(W1) + prep_w(W2) co-scheduled
    prep_fused<<<3112, 512, 0, stream>>>(c1, c2, f2, W1, W2, pk, f2t, W1s, W2s);

    gemm_kernel<12, false><<<1024, 256, 0, stream>>>(
        W1s, f1, nullptr, f2t, pk, nullptr, nullptr, y1kc, P);
    bn_reduce<<<256, 256, 0, stream>>>(P, g1, be1, scale1, shift1);

    gemm_kernel<8, true><<<1024, 256, 0, stream>>>(
        W2s, nullptr, y1kc, nullptr, nullptr, scale1, shift1, y2kc, P);
    bn_reduce<<<256, 256, 0, stream>>>(P, g2, be2, scale2, shift2);

    final_bn_relu<<<dim3(N1 / 1024, 32, BATCH), 256, 0, stream>>>(y2kc, scale2, shift2, out);
}